// Round 5
// baseline (187.524 us; speedup 1.0000x reference)
//
#include <hip/hip_runtime.h>

// B=32, T=2048, D=128, H=256. fp32 in/out.
// 3 dispatches:
//   1) wsplit: W1,W2 -> exact fp16 plane pairs (x = a+b to 2^-21 rel)
//   2) gemm1:  h1 = x @ W1^T + b1 via MFMA fp16, 3 passes (aa, ab, ba)
//   3) fused2: per (b, 256-t chunk) block: spec-scan1 (warmup 128) -> GEMM2
//      (spikes from LDS, W2 planes from L2) -> spec-scan2 -> residual+LN.
//      Spikes/h2 never touch HBM. Numerics identical to R4 (passed).
//
// ws: A1 f32 [65536][256] @ 0 (64 MB); Wp fp16 4 planes x 32768 @ 64 MB.

typedef _Float16 half8 __attribute__((ext_vector_type(8)));
typedef float f32x4 __attribute__((ext_vector_type(4)));

#define MFMA_F16(a, b, c) __builtin_amdgcn_mfma_f32_16x16x32_f16(a, b, c, 0, 0, 0)

__device__ __forceinline__ unsigned short h2u(_Float16 h) {
    union { _Float16 h; unsigned short u; } x; x.h = h; return x.u;
}

__device__ __forceinline__ void store16(unsigned short* dst, const unsigned short* s) {
    uint4 u0, u1;
    u0.x = s[0]  | ((unsigned)s[1]  << 16); u0.y = s[2]  | ((unsigned)s[3]  << 16);
    u0.z = s[4]  | ((unsigned)s[5]  << 16); u0.w = s[6]  | ((unsigned)s[7]  << 16);
    u1.x = s[8]  | ((unsigned)s[9]  << 16); u1.y = s[10] | ((unsigned)s[11] << 16);
    u1.z = s[12] | ((unsigned)s[13] << 16); u1.w = s[14] | ((unsigned)s[15] << 16);
    *(uint4*)dst = u0; *(uint4*)(dst + 8) = u1;
}

// Split W1 (32768) and W2 (32768) into 2 fp16 planes each.
__global__ __launch_bounds__(256) void wsplit_kernel(
    const float* __restrict__ W1, const float* __restrict__ W2,
    unsigned short* __restrict__ out)
{
    int i = blockIdx.x * 256 + threadIdx.x;          // 0..65535
    const float* src = (i < 32768) ? W1 : W2;
    unsigned short* dst = out + ((i < 32768) ? 0 : 2 * 32768);
    int j = i & 32767;
    float v = src[j];
    _Float16 a = (_Float16)v;
    float r = v - (float)a;
    _Float16 b = (_Float16)r;
    dst[j] = h2u(a); dst[32768 + j] = h2u(b);
}

// GEMM1: C[m][n] = sum_k X[m][k]*W1[n][k] + b1[n]. X fp32 split in-kernel,
// W1 planes fp16 read as B-fragments straight from global (L2-resident).
// Block 128x128, 4 waves, 3 MFMA passes, K=128. C fp32 ldc=256.
__global__ __launch_bounds__(256, 3) void gemm1_kernel(
    const float* __restrict__ X,
    const unsigned short* __restrict__ W1a,
    const unsigned short* __restrict__ W1b,
    const float* __restrict__ bias,
    float* __restrict__ C)
{
    constexpr int LDSX = 40;   // 20-word row stride: b128 A-frag reads 2-way max
    __shared__ unsigned short As[2][128 * LDSX];

    const int tid = threadIdx.x;
    const int lane = tid & 63;
    const int wave = tid >> 6;
    const int waveM = (wave >> 1) * 64;
    const int waveN = (wave & 1) * 64;
    const int mBase = blockIdx.x * 128;
    const int nBase = blockIdx.y * 128;
    const int lr = tid >> 1;            // staging row 0..127
    const int lh = (tid & 1) * 16;      // k offset 0/16
    const int fr = lane & 15;
    const int fo = (lane >> 4) * 8;

    f32x4 acc[4][4];
#pragma unroll
    for (int i = 0; i < 4; ++i)
#pragma unroll
        for (int j = 0; j < 4; ++j) acc[i][j] = (f32x4){0.f, 0.f, 0.f, 0.f};

    const float* xp = X + (size_t)(mBase + lr) * 128 + lh;

#pragma unroll
    for (int k0 = 0; k0 < 128; k0 += 32) {
        float4 f0 = *(const float4*)(xp + k0);
        float4 f1 = *(const float4*)(xp + k0 + 4);
        float4 f2 = *(const float4*)(xp + k0 + 8);
        float4 f3 = *(const float4*)(xp + k0 + 12);

        // B-fragments from global (overlap with split+staging)
        half8 bf[4][2];
#pragma unroll
        for (int j = 0; j < 4; ++j) {
            size_t n = (size_t)(nBase + waveN + j * 16 + fr);
            bf[j][0] = *(const half8*)&W1a[n * 128 + k0 + fo];
            bf[j][1] = *(const half8*)&W1b[n * 128 + k0 + fo];
        }

        unsigned short sa[16], sb[16];
        {
            float fs[16] = {f0.x, f0.y, f0.z, f0.w, f1.x, f1.y, f1.z, f1.w,
                            f2.x, f2.y, f2.z, f2.w, f3.x, f3.y, f3.z, f3.w};
#pragma unroll
            for (int q = 0; q < 16; ++q) {
                _Float16 a = (_Float16)fs[q];
                float r = fs[q] - (float)a;
                _Float16 b = (_Float16)r;
                sa[q] = h2u(a); sb[q] = h2u(b);
            }
        }

        __syncthreads();
        store16(&As[0][lr * LDSX + lh], sa);
        store16(&As[1][lr * LDSX + lh], sb);
        __syncthreads();

        half8 a1[4], a2[4];
#pragma unroll
        for (int i = 0; i < 4; ++i) {
            int ro = (waveM + i * 16 + fr) * LDSX + fo;
            a1[i] = *(const half8*)&As[0][ro];
            a2[i] = *(const half8*)&As[1][ro];
        }
#pragma unroll
        for (int j = 0; j < 4; ++j)
#pragma unroll
            for (int i = 0; i < 4; ++i) {
                acc[i][j] = MFMA_F16(a1[i], bf[j][0], acc[i][j]);   // aa
                acc[i][j] = MFMA_F16(a1[i], bf[j][1], acc[i][j]);   // ab
                acc[i][j] = MFMA_F16(a2[i], bf[j][0], acc[i][j]);   // ba
            }
    }

    const int qr = (lane >> 4) * 4;   // C/D: col=lane&15, row=quad*4+reg
#pragma unroll
    for (int j = 0; j < 4; ++j) {
        float bv = bias[nBase + waveN + j * 16 + fr];
#pragma unroll
        for (int i = 0; i < 4; ++i) {
            float* cp = C + (size_t)(mBase + waveM + i * 16 + qr) * 256
                          + (nBase + waveN + j * 16 + fr);
#pragma unroll
            for (int r = 0; r < 4; ++r)
                cp[(size_t)r * 256] = acc[i][j][r] + bv;
        }
    }
}

// Fused tail: scan1 -> GEMM2 -> scan2 -> residual+LN.
// grid (8, 32) = 256 blocks, 256 threads. Chunk = 256 t (4 main subchunks of
// 64) + 128 t warmup (2 subchunks). One 33 KB LDS buffer aliased:
//   spikes fp16 [64][264]  (MFMA-A layout, 132-word rows: aligned16, 2-way max)
//   h2/y  f32  [64][132]
__global__ __launch_bounds__(256, 1) void fused2_kernel(
    const float* __restrict__ A1,           // [65536][256] h1 pre-activation
    const unsigned short* __restrict__ W2a, // [128][256] fp16 plane
    const unsigned short* __restrict__ W2b,
    const float* __restrict__ b2,
    const float* __restrict__ X,            // [65536][128]
    const float* __restrict__ lnw, const float* __restrict__ lnb,
    float* __restrict__ out)
{
    constexpr int SPX = 264;                // shorts per spike row (= 132 floats)
    __shared__ __align__(16) unsigned short spU[64 * SPX];
    _Float16* spH = (_Float16*)spU;
    float* h2 = (float*)spU;                // stride 132 floats, aliased

    const int tid = threadIdx.x;
    const int lane = tid & 63;
    const int wave = tid >> 6;
    const int fr = lane & 15;
    const int fo8 = (lane >> 4) * 8;
    const int qr = (lane >> 4) * 4;
    const int waveT = (wave & 1) * 32;      // t-rows of this wave's GEMM2 tile
    const int waveN = (wave >> 1) * 64;     // n-cols
    const int b = blockIdx.y;
    const int t0 = blockIdx.x * 256;
    const int s0 = (blockIdx.x == 0) ? 2 : 0;

    const float* __restrict__ a1p = A1 + (size_t)b * 2048 * 256 + tid;
    const float* __restrict__ xp  = X  + (size_t)b * 2048 * 128 + tid;

    float bv2[4];
#pragma unroll
    for (int j = 0; j < 4; ++j) bv2[j] = b2[waveN + j * 16 + fr];
    const float2 wv = *(const float2*)(lnw + lane * 2);
    const float2 bb = *(const float2*)(lnb + lane * 2);

    float v1 = 0.0f, v2 = 0.0f;
    float cur[64], nxt[64];

    for (int s = s0; s < 6; ++s) {
        const int tbase = t0 - 128 + s * 64;

        if (s == s0) {
#pragma unroll
            for (int k = 0; k < 64; ++k)
                cur[k] = a1p[(size_t)(tbase + k) * 256];
        }
        __syncthreads();   // prior phase's LDS readers done; safe to write spikes

        // ---- Phase 1: scan1 (256 channels = 256 threads) ----
#pragma unroll
        for (int k = 0; k < 64; ++k) {
            float h = v1 + (cur[k] - v1) * 0.5f;
            bool sp = (h >= 1.0f);
            v1 = sp ? 0.0f : h;
            spU[k * SPX + tid] = sp ? (unsigned short)0x3C00 : (unsigned short)0;
        }
        __syncthreads();   // spikes ready

        // prefetch next subchunk's A1 (drained by post-GEMM2 barrier; latency
        // hidden behind the MFMA loop)
        if (s < 5) {
#pragma unroll
            for (int k = 0; k < 64; ++k)
                nxt[k] = a1p[(size_t)(tbase + 64 + k) * 256];
        }

        // ---- Phase 2: GEMM2, wave tile 32 t x 64 n, K=256, 2 planes ----
        f32x4 acc[2][4];
#pragma unroll
        for (int i = 0; i < 2; ++i)
#pragma unroll
            for (int j = 0; j < 4; ++j) acc[i][j] = (f32x4){0.f, 0.f, 0.f, 0.f};

        half8 bf[2][4][2];
#pragma unroll
        for (int j = 0; j < 4; ++j) {
            size_t n = (size_t)(waveN + j * 16 + fr) * 256;
            bf[0][j][0] = *(const half8*)&W2a[n + 0 * 32 + fo8];
            bf[0][j][1] = *(const half8*)&W2b[n + 0 * 32 + fo8];
            bf[1][j][0] = *(const half8*)&W2a[n + 1 * 32 + fo8];
            bf[1][j][1] = *(const half8*)&W2b[n + 1 * 32 + fo8];
        }
#pragma unroll
        for (int ks = 0; ks < 8; ++ks) {
            half8 a0 = *(const half8*)&spH[(waveT + fr) * SPX + ks * 32 + fo8];
            half8 a1f = *(const half8*)&spH[(waveT + 16 + fr) * SPX + ks * 32 + fo8];
            half8 (&bc)[4][2] = bf[ks & 1];
#pragma unroll
            for (int j = 0; j < 4; ++j) {
                acc[0][j] = MFMA_F16(a0,  bc[j][0], acc[0][j]);
                acc[0][j] = MFMA_F16(a0,  bc[j][1], acc[0][j]);
                acc[1][j] = MFMA_F16(a1f, bc[j][0], acc[1][j]);
                acc[1][j] = MFMA_F16(a1f, bc[j][1], acc[1][j]);
            }
            if (ks < 6) {
#pragma unroll
                for (int j = 0; j < 4; ++j) {
                    size_t n = (size_t)(waveN + j * 16 + fr) * 256;
                    bf[ks & 1][j][0] = *(const half8*)&W2a[n + (ks + 2) * 32 + fo8];
                    bf[ks & 1][j][1] = *(const half8*)&W2b[n + (ks + 2) * 32 + fo8];
                }
            }
        }
        __syncthreads();   // all spike reads done; buffer reusable as h2

        // ---- Phase 3: h2 = acc + b2 -> LDS ----
#pragma unroll
        for (int i = 0; i < 2; ++i)
#pragma unroll
            for (int j = 0; j < 4; ++j) {
                int col = waveN + j * 16 + fr;
#pragma unroll
                for (int r = 0; r < 4; ++r)
                    h2[(waveT + i * 16 + qr + r) * 132 + col] = acc[i][j][r] + bv2[j];
            }
        __syncthreads();   // h2 ready

        // ---- Phase 4: scan2 (128 channels = threads 0..127) ----
        const bool mainsub = (s >= 2);
        if (tid < 128) {
            for (int tb = 0; tb < 64; tb += 16) {
                float xv[16], hh[16];
                if (mainsub) {
#pragma unroll
                    for (int k = 0; k < 16; ++k)
                        xv[k] = xp[(size_t)(tbase + tb + k) * 128];
                }
#pragma unroll
                for (int k = 0; k < 16; ++k)
                    hh[k] = h2[(tb + k) * 132 + tid];
#pragma unroll
                for (int k = 0; k < 16; ++k) {
                    float h = v2 + (hh[k] - v2) * 0.5f;
                    bool sp = (h >= 1.0f);
                    v2 = sp ? 0.0f : h;
                    if (mainsub)
                        h2[(tb + k) * 132 + tid] = xv[k] + (sp ? 1.0f : 0.0f);
                }
            }
        }

        // ---- Phase 5: LN + store (main subchunks only) ----
        if (mainsub) {
            __syncthreads();   // y ready
#pragma unroll 4
            for (int rr = 0; rr < 16; ++rr) {
                int row = wave * 16 + rr;
                float2 y = *(const float2*)&h2[row * 132 + lane * 2];
                float sum = y.x + y.y;
                float ss = y.x * y.x + y.y * y.y;
#pragma unroll
                for (int off = 32; off > 0; off >>= 1) {
                    sum += __shfl_xor(sum, off, 64);
                    ss  += __shfl_xor(ss, off, 64);
                }
                float mu = sum * (1.0f / 128.0f);
                float var = ss * (1.0f / 128.0f) - mu * mu;
                float inv = rsqrtf(var + 1e-5f);
                float2 o;
                o.x = (y.x - mu) * inv * wv.x + bb.x;
                o.y = (y.y - mu) * inv * wv.y + bb.y;
                *(float2*)(out + (size_t)(b * 2048 + tbase + row) * 128 + lane * 2) = o;
            }
        }

        if (s < 5) {
#pragma unroll
            for (int k = 0; k < 64; ++k) cur[k] = nxt[k];
        }
    }
}

extern "C" void kernel_launch(void* const* d_in, const int* in_sizes, int n_in,
                              void* d_out, int out_size, void* d_ws, size_t ws_size,
                              hipStream_t stream)
{
    const float* x   = (const float*)d_in[0];
    const float* W1  = (const float*)d_in[1];
    const float* b1  = (const float*)d_in[2];
    const float* W2  = (const float*)d_in[3];
    const float* b2  = (const float*)d_in[4];
    const float* lnw = (const float*)d_in[5];
    const float* lnb = (const float*)d_in[6];
    float* out = (float*)d_out;

    char* ws = (char*)d_ws;
    float* A1 = (float*)ws;                                  // [65536][256]
    unsigned short* Wp = (unsigned short*)(ws + 67108864);   // 4 planes x 32768

    wsplit_kernel<<<256, 256, 0, stream>>>(W1, W2, Wp);
    dim3 gG1(512, 2);
    gemm1_kernel<<<gG1, 256, 0, stream>>>(x, Wp, Wp + 32768, b1, A1);
    dim3 gF(8, 32);
    fused2_kernel<<<gF, 256, 0, stream>>>(A1, Wp + 65536, Wp + 98304, b2,
                                          x, lnw, lnb, out);
}

// Round 6
// 153.310 us; speedup vs baseline: 1.2232x; 1.2232x over previous
//
#include <hip/hip_runtime.h>

// B=32, T=2048, D=128, H=256. fp32 in/out.
// 2 dispatches:
//  1) wsplit: W1,W2 -> exact fp16 plane pairs (w = a+b, 2^-21 rel)
//  2) mega:   per (b, 256-t chunk) block (512 thr, 8 waves):
//       x -> GEMM1 (3-pass fp16 MFMA) -> spec-scan1 -> GEMM2 (2-pass)
//         -> spec-scan2 -> residual+LN -> out
//     All W fragments REGISTER-PERSISTENT (loaded once per block): wave w
//     owns h in [32w,32w+32) for GEMM1 and d = 16w..16w+16 for GEMM2.
//     Subchunk = 32 t; warmup = 128 t (4 subchunks); 12 subchunks total.
//     Numerics instruction-identical to R5 (passed, absmax 0.015625).
//
// LDS 50.4 KB: buf1 f32 [32][258] (h1 -> h2/s2 in cols 0..127)
//              buf2 fp16 2 x [32][136] x-planes (aliased: spikes [32][264])
// ws: Wp fp16 4 planes x 32768 @ 0.

typedef _Float16 half8 __attribute__((ext_vector_type(8)));
typedef float f32x4 __attribute__((ext_vector_type(4)));

#define MFMA_F16(a, b, c) __builtin_amdgcn_mfma_f32_16x16x32_f16(a, b, c, 0, 0, 0)

__device__ __forceinline__ unsigned short h2u(_Float16 h) {
    union { _Float16 h; unsigned short u; } x; x.h = h; return x.u;
}

// Split W1 (32768) and W2 (32768) into 2 fp16 planes each.
__global__ __launch_bounds__(256) void wsplit_kernel(
    const float* __restrict__ W1, const float* __restrict__ W2,
    unsigned short* __restrict__ out)
{
    int i = blockIdx.x * 256 + threadIdx.x;          // 0..65535
    const float* src = (i < 32768) ? W1 : W2;
    unsigned short* dst = out + ((i < 32768) ? 0 : 2 * 32768);
    int j = i & 32767;
    float v = src[j];
    _Float16 a = (_Float16)v;
    float r = v - (float)a;
    _Float16 b = (_Float16)r;
    dst[j] = h2u(a); dst[32768 + j] = h2u(b);
}

__global__ __launch_bounds__(512, 1) void mega_kernel(
    const float* __restrict__ X,
    const unsigned short* __restrict__ W1a, const unsigned short* __restrict__ W1b,
    const unsigned short* __restrict__ W2a, const unsigned short* __restrict__ W2b,
    const float* __restrict__ b1, const float* __restrict__ b2,
    const float* __restrict__ lnw, const float* __restrict__ lnb,
    float* __restrict__ out)
{
    __shared__ __align__(16) float buf1[32 * 258];           // 33.0 KB
    __shared__ __align__(16) unsigned short buf2[2 * 32 * 136]; // 17.4 KB
    _Float16* xA0 = (_Float16*)buf2;                 // plane a, [32][136]
    _Float16* xA1 = (_Float16*)(buf2 + 32 * 136);    // plane b
    _Float16* spH = (_Float16*)buf2;                 // spikes [32][264] (alias)
    unsigned short* spU = buf2;

    const int tid = threadIdx.x;            // 0..511
    const int lane = tid & 63;
    const int w = tid >> 6;                 // wave 0..7
    const int fr = lane & 15;
    const int fo8 = (lane >> 4) * 8;
    const int qr = (lane >> 4) * 4;
    const int b = blockIdx.y;
    const int t0 = blockIdx.x * 256;
    const int s0 = (blockIdx.x == 0) ? 4 : 0;

    // ---- persistent weight fragments (loaded once) ----
    half8 b1f[2][4][2];   // [j][k0][plane]; h-row = 32w + 16j + fr
#pragma unroll
    for (int j = 0; j < 2; ++j) {
        const size_t n = (size_t)(32 * w + 16 * j + fr) * 128;
#pragma unroll
        for (int k0 = 0; k0 < 4; ++k0) {
            b1f[j][k0][0] = *(const half8*)&W1a[n + k0 * 32 + fo8];
            b1f[j][k0][1] = *(const half8*)&W1b[n + k0 * 32 + fo8];
        }
    }
    half8 b2f[8][2];      // [ks][plane]; d-row = 16w + fr
    {
        const size_t d = (size_t)(16 * w + fr) * 256;
#pragma unroll
        for (int ks = 0; ks < 8; ++ks) {
            b2f[ks][0] = *(const half8*)&W2a[d + ks * 32 + fo8];
            b2f[ks][1] = *(const half8*)&W2b[d + ks * 32 + fo8];
        }
    }
    const float b1v0 = b1[32 * w + fr];
    const float b1v1 = b1[32 * w + 16 + fr];
    const float b2v  = b2[16 * w + fr];
    const float2 wv = *(const float2*)(lnw + lane * 2);
    const float2 bbv = *(const float2*)(lnb + lane * 2);

    float v1 = 0.0f, v2 = 0.0f;

    for (int s = s0; s < 12; ++s) {
        const int tbase = t0 - 128 + s * 32;
        const bool mainsub = (s >= 4);

        // ---- P0: load x tile [32 t][128 d], split to fp16 planes in LDS ----
#pragma unroll
        for (int qq = 0; qq < 2; ++qq) {
            int idx4 = qq * 512 + tid;           // 0..1023 float4 slots
            int row = idx4 >> 5;                 // 0..31
            int c4 = (idx4 & 31) * 4;            // 0..124
            float4 xv = *(const float4*)&X[(size_t)(b * 2048 + tbase + row) * 128 + c4];
            _Float16 a0 = (_Float16)xv.x; _Float16 e0 = (_Float16)(xv.x - (float)a0);
            _Float16 a1 = (_Float16)xv.y; _Float16 e1 = (_Float16)(xv.y - (float)a1);
            _Float16 a2 = (_Float16)xv.z; _Float16 e2 = (_Float16)(xv.z - (float)a2);
            _Float16 a3 = (_Float16)xv.w; _Float16 e3 = (_Float16)(xv.w - (float)a3);
            ushort4 ua = {h2u(a0), h2u(a1), h2u(a2), h2u(a3)};
            ushort4 ub = {h2u(e0), h2u(e1), h2u(e2), h2u(e3)};
            *(ushort4*)&buf2[row * 136 + c4] = ua;
            *(ushort4*)&buf2[32 * 136 + row * 136 + c4] = ub;
        }
        __syncthreads();   // B1: xA ready (also fences prev LN reads vs h1 writes)

        // ---- G1: h1[t][h] = sum_k x*W1 (3 passes: aa, ab, ba) ----
        {
            f32x4 acc1[2][2];
#pragma unroll
            for (int i = 0; i < 2; ++i)
#pragma unroll
                for (int j = 0; j < 2; ++j) acc1[i][j] = (f32x4){0.f, 0.f, 0.f, 0.f};
#pragma unroll
            for (int k0 = 0; k0 < 4; ++k0) {
                half8 a1r[2], a2r[2];
#pragma unroll
                for (int i = 0; i < 2; ++i) {
                    int off = (i * 16 + fr) * 136 + k0 * 32 + fo8;
                    a1r[i] = *(const half8*)&xA0[off];
                    a2r[i] = *(const half8*)&xA1[off];
                }
#pragma unroll
                for (int i = 0; i < 2; ++i)
#pragma unroll
                    for (int j = 0; j < 2; ++j) {
                        acc1[i][j] = MFMA_F16(a1r[i], b1f[j][k0][0], acc1[i][j]);
                        acc1[i][j] = MFMA_F16(a1r[i], b1f[j][k0][1], acc1[i][j]);
                        acc1[i][j] = MFMA_F16(a2r[i], b1f[j][k0][0], acc1[i][j]);
                    }
            }
#pragma unroll
            for (int i = 0; i < 2; ++i)
#pragma unroll
                for (int j = 0; j < 2; ++j) {
                    int col = 32 * w + 16 * j + fr;
                    float bias = j ? b1v1 : b1v0;
#pragma unroll
                    for (int r = 0; r < 4; ++r)
                        buf1[(i * 16 + qr + r) * 258 + col] = acc1[i][j][r] + bias;
                }
        }
        __syncthreads();   // B2: h1 ready (xA consumed)

        // ---- scan1: 256 channels (waves 0..3) ----
        if (tid < 256) {
            float hh[32];
#pragma unroll
            for (int t = 0; t < 32; ++t) hh[t] = buf1[t * 258 + tid];
#pragma unroll
            for (int t = 0; t < 32; ++t) {
                float h = v1 + (hh[t] - v1) * 0.5f;
                bool sp = (h >= 1.0f);
                v1 = sp ? 0.0f : h;
                spU[t * 264 + tid] = sp ? (unsigned short)0x3C00 : (unsigned short)0;
            }
        }
        __syncthreads();   // B3: spikes ready (h1 consumed)

        // ---- G2: h2[t][d] = sum_h spikes*W2 (2 passes) ----
        {
            f32x4 acc2[2];
            acc2[0] = (f32x4){0.f, 0.f, 0.f, 0.f};
            acc2[1] = (f32x4){0.f, 0.f, 0.f, 0.f};
#pragma unroll
            for (int ks = 0; ks < 8; ++ks) {
                half8 s0r = *(const half8*)&spH[fr * 264 + ks * 32 + fo8];
                half8 s1r = *(const half8*)&spH[(16 + fr) * 264 + ks * 32 + fo8];
                acc2[0] = MFMA_F16(s0r, b2f[ks][0], acc2[0]);
                acc2[0] = MFMA_F16(s0r, b2f[ks][1], acc2[0]);
                acc2[1] = MFMA_F16(s1r, b2f[ks][0], acc2[1]);
                acc2[1] = MFMA_F16(s1r, b2f[ks][1], acc2[1]);
            }
            int col = 16 * w + fr;
#pragma unroll
            for (int i = 0; i < 2; ++i)
#pragma unroll
                for (int r = 0; r < 4; ++r)
                    buf1[(i * 16 + qr + r) * 258 + col] = acc2[i][r] + b2v;
        }
        __syncthreads();   // B4: h2 ready (spike reads done)

        // ---- scan2: 128 channels (waves 0..1); s2 overwrites h2 in place ----
        if (tid < 128) {
            float hh[32];
#pragma unroll
            for (int t = 0; t < 32; ++t) hh[t] = buf1[t * 258 + tid];
#pragma unroll
            for (int t = 0; t < 32; ++t) {
                float h = v2 + (hh[t] - v2) * 0.5f;
                bool sp = (h >= 1.0f);
                v2 = sp ? 0.0f : h;
                if (mainsub) buf1[t * 258 + tid] = sp ? 1.0f : 0.0f;
            }
        }

        // ---- LN + store (main subchunks only) ----
        if (mainsub) {
            __syncthreads();   // B5: s2 ready
#pragma unroll
            for (int rr = 0; rr < 4; ++rr) {
                int row = w * 4 + rr;
                float2 xg = *(const float2*)&X[(size_t)(b * 2048 + tbase + row) * 128 + lane * 2];
                float y0 = xg.x + buf1[row * 258 + lane * 2];
                float y1 = xg.y + buf1[row * 258 + lane * 2 + 1];
                float sum = y0 + y1;
                float ss = y0 * y0 + y1 * y1;
#pragma unroll
                for (int off = 32; off > 0; off >>= 1) {
                    sum += __shfl_xor(sum, off, 64);
                    ss  += __shfl_xor(ss, off, 64);
                }
                float mu = sum * (1.0f / 128.0f);
                float var = ss * (1.0f / 128.0f) - mu * mu;
                float inv = rsqrtf(var + 1e-5f);
                float2 o;
                o.x = (y0 - mu) * inv * wv.x + bbv.x;
                o.y = (y1 - mu) * inv * wv.y + bbv.y;
                *(float2*)(out + (size_t)(b * 2048 + tbase + row) * 128 + lane * 2) = o;
            }
        }
        // next P0 writes buf2 only; scan2/LN buf1 reads are fenced by next B1.
    }
}

extern "C" void kernel_launch(void* const* d_in, const int* in_sizes, int n_in,
                              void* d_out, int out_size, void* d_ws, size_t ws_size,
                              hipStream_t stream)
{
    const float* x   = (const float*)d_in[0];
    const float* W1  = (const float*)d_in[1];
    const float* b1  = (const float*)d_in[2];
    const float* W2  = (const float*)d_in[3];
    const float* b2  = (const float*)d_in[4];
    const float* lnw = (const float*)d_in[5];
    const float* lnb = (const float*)d_in[6];
    float* out = (float*)d_out;

    unsigned short* Wp = (unsigned short*)d_ws;   // 4 planes x 32768 fp16

    wsplit_kernel<<<256, 256, 0, stream>>>(W1, W2, Wp);
    dim3 gM(8, 32);   // chunks x batch = 256 blocks (1/CU)
    mega_kernel<<<gM, 512, 0, stream>>>(x, Wp, Wp + 32768, Wp + 65536, Wp + 98304,
                                        b1, b2, lnw, lnb, out);
}

// Round 7
// 149.640 us; speedup vs baseline: 1.2532x; 1.0245x over previous
//
#include <hip/hip_runtime.h>

// B=32, T=2048, D=128, H=256. fp32 in/out. SINGLE dispatch.
// Wave-specialized pipelined megakernel, grid (8,32), 512 threads:
//   S-group (waves 0-3): scan1(s) -> GEMM2(s) -> scan2(s) -> [LN(s) w/ all]
//   G-group (waves 4-7): P0(s+1) x-load/split -> GEMM1(s+1)
// running concurrently; 3 barriers/subchunk. Subchunk = 16 t, chunk = 256 t,
// warmup = 128 t (8 subchunks), 24 subchunks total.
// Weights register-persistent in a SHARED wf[32] half8 array (G-waves: W1
// 2-plane split; S-waves: W2 2-plane split) -> ~190 VGPR, 2 waves/SIMD.
// All accumulation orders instruction-identical to R6 (absmax 0.015625).
//
// LDS 50,688 B:
//   hbuf[2][16*260] f32 (h1 ping-pong; h2/s2 reuse the dead parity)
//   xabuf[2][2][16*136] fp16 (x-plane ping-pong; spikes [16][264] overlay
//   the dead parity)

typedef _Float16 half8 __attribute__((ext_vector_type(8)));
typedef float f32x4 __attribute__((ext_vector_type(4)));

#define MFMA_F16(a, b, c) __builtin_amdgcn_mfma_f32_16x16x32_f16(a, b, c, 0, 0, 0)

__device__ __forceinline__ unsigned short h2u(_Float16 h) {
    union { _Float16 h; unsigned short u; } x; x.h = h; return x.u;
}

__device__ __forceinline__ void split8(float4 f0, float4 f1, half8& a, half8& b) {
    float fs[8] = {f0.x, f0.y, f0.z, f0.w, f1.x, f1.y, f1.z, f1.w};
    half8 ha, hb;
#pragma unroll
    for (int q = 0; q < 8; ++q) {
        ha[q] = (_Float16)fs[q];
        hb[q] = (_Float16)(fs[q] - (float)ha[q]);
    }
    a = ha; b = hb;
}

__global__ __launch_bounds__(512, 1) void mega_kernel(
    const float* __restrict__ X,
    const float* __restrict__ W1, const float* __restrict__ W2,
    const float* __restrict__ b1, const float* __restrict__ b2,
    const float* __restrict__ lnw, const float* __restrict__ lnb,
    float* __restrict__ out)
{
    __shared__ __align__(16) float hbuf[2][16 * 260];               // 33280 B
    __shared__ __align__(16) unsigned short xabuf[2][2][16 * 136];  // 17408 B

    const int tid = threadIdx.x;
    const int lane = tid & 63;
    const int w = tid >> 6;                 // wave 0..7
    const bool isS = (tid < 256);           // S-group: waves 0-3
    const int sg = w;                       // S-wave id (valid if isS)
    const int gg = w - 4;                   // G-wave id (valid if !isS)
    const int fr = lane & 15;
    const int fo8 = (lane >> 4) * 8;
    const int qr = (lane >> 4) * 4;
    const int b = blockIdx.y;
    const int t0 = blockIdx.x * 256;
    const int s0 = (blockIdx.x == 0) ? 8 : 0;

    const float* __restrict__ xbase = X + (size_t)b * 2048 * 128;
    float* __restrict__ obase = out + (size_t)b * 2048 * 128;

    // ---- shared-physical weight fragments ----
    half8 wf[32];
    float bias0[4];
    if (isS) {
        // W2 slice: d-rows 32sg+16j+fr, j<2; wf[(j*8+ks)*2+p]
#pragma unroll
        for (int j = 0; j < 2; ++j) {
            const size_t d = (size_t)(32 * sg + 16 * j + fr) * 256;
#pragma unroll
            for (int ks = 0; ks < 8; ++ks) {
                float4 f0 = *(const float4*)&W2[d + ks * 32 + fo8];
                float4 f1 = *(const float4*)&W2[d + ks * 32 + fo8 + 4];
                split8(f0, f1, wf[(j * 8 + ks) * 2], wf[(j * 8 + ks) * 2 + 1]);
            }
            bias0[j] = b2[32 * sg + 16 * j + fr];
        }
    } else {
        // W1 slice: h-rows 64gg+16j+fr, j<4; wf[(j*4+k0)*2+p]
#pragma unroll
        for (int j = 0; j < 4; ++j) {
            const size_t n = (size_t)(64 * gg + 16 * j + fr) * 128;
#pragma unroll
            for (int k0 = 0; k0 < 4; ++k0) {
                float4 f0 = *(const float4*)&W1[n + k0 * 32 + fo8];
                float4 f1 = *(const float4*)&W1[n + k0 * 32 + fo8 + 4];
                split8(f0, f1, wf[(j * 4 + k0) * 2], wf[(j * 4 + k0) * 2 + 1]);
            }
            bias0[j] = b1[64 * gg + 16 * j + fr];
        }
    }
    const float2 wv = *(const float2*)(lnw + lane * 2);
    const float2 bbv = *(const float2*)(lnb + lane * 2);

    float v1 = 0.0f, v2 = 0.0f;
    float4 pfx[2];
    const int tg = tid & 255;               // G-thread index (tid-256 for G)
    const int prow = tg >> 5;               // P0 row 0..7 (q adds +8)
    const int pc4 = (tg & 31) * 4;          // P0 col 0..124

    // ---- prologue: stage xA(s0), prime pfx(s0+1) ----
    if (!isS) {
        const int tb0 = t0 - 128 + s0 * 16;
#pragma unroll
        for (int q = 0; q < 2; ++q) {
            float4 xv = *(const float4*)&xbase[(size_t)(tb0 + prow + q * 8) * 128 + pc4];
            half8 a, e; split8(xv, xv, a, e);   // only low4 used below
            _Float16 a0 = (_Float16)xv.x, e0 = (_Float16)(xv.x - (float)a0);
            _Float16 a1 = (_Float16)xv.y, e1 = (_Float16)(xv.y - (float)a1);
            _Float16 a2 = (_Float16)xv.z, e2 = (_Float16)(xv.z - (float)a2);
            _Float16 a3 = (_Float16)xv.w, e3 = (_Float16)(xv.w - (float)a3);
            ushort4 ua = {h2u(a0), h2u(a1), h2u(a2), h2u(a3)};
            ushort4 ue = {h2u(e0), h2u(e1), h2u(e2), h2u(e3)};
            *(ushort4*)&xabuf[s0 & 1][0][(prow + q * 8) * 136 + pc4] = ua;
            *(ushort4*)&xabuf[s0 & 1][1][(prow + q * 8) * 136 + pc4] = ue;
        }
#pragma unroll
        for (int q = 0; q < 2; ++q)
            pfx[q] = *(const float4*)&xbase[(size_t)(tb0 + 16 + prow + q * 8) * 128 + pc4];
    }
    __syncthreads();
    if (!isS) {
        // G1(s0) -> hbuf[s0&1]
        const _Float16* xa0 = (const _Float16*)&xabuf[s0 & 1][0][0];
        const _Float16* xa1 = (const _Float16*)&xabuf[s0 & 1][1][0];
        f32x4 acc[4];
#pragma unroll
        for (int j = 0; j < 4; ++j) acc[j] = (f32x4){0.f, 0.f, 0.f, 0.f};
#pragma unroll
        for (int k0 = 0; k0 < 4; ++k0) {
            half8 a0 = *(const half8*)&xa0[fr * 136 + k0 * 32 + fo8];
            half8 a1 = *(const half8*)&xa1[fr * 136 + k0 * 32 + fo8];
#pragma unroll
            for (int j = 0; j < 4; ++j) {
                acc[j] = MFMA_F16(a0, wf[(j * 4 + k0) * 2], acc[j]);
                acc[j] = MFMA_F16(a0, wf[(j * 4 + k0) * 2 + 1], acc[j]);
                acc[j] = MFMA_F16(a1, wf[(j * 4 + k0) * 2], acc[j]);
            }
        }
#pragma unroll
        for (int j = 0; j < 4; ++j) {
            int col = 64 * gg + 16 * j + fr;
#pragma unroll
            for (int r = 0; r < 4; ++r)
                hbuf[s0 & 1][(qr + r) * 260 + col] = acc[j][r] + bias0[j];
        }
    }
    __syncthreads();

    // ---- main loop ----
    for (int s = s0; s < 24; ++s) {
        const int tbase = t0 - 128 + s * 16;
        const bool mainsub = (s >= 8);

        // ---- step 1: S: scan1(s); G: P0(s+1) ----
        if (isS) {
            unsigned short* spk = &xabuf[s & 1][0][0];   // [16][264] overlay
            float hh[16];
#pragma unroll
            for (int t = 0; t < 16; ++t) hh[t] = hbuf[s & 1][t * 260 + tid];
#pragma unroll
            for (int t = 0; t < 16; ++t) {
                float h = v1 + (hh[t] - v1) * 0.5f;
                bool sp = (h >= 1.0f);
                v1 = sp ? 0.0f : h;
                spk[t * 264 + tid] = sp ? (unsigned short)0x3C00 : (unsigned short)0;
            }
        } else if (s < 23) {
#pragma unroll
            for (int q = 0; q < 2; ++q) {
                float4 xv = pfx[q];
                _Float16 a0 = (_Float16)xv.x, e0 = (_Float16)(xv.x - (float)a0);
                _Float16 a1 = (_Float16)xv.y, e1 = (_Float16)(xv.y - (float)a1);
                _Float16 a2 = (_Float16)xv.z, e2 = (_Float16)(xv.z - (float)a2);
                _Float16 a3 = (_Float16)xv.w, e3 = (_Float16)(xv.w - (float)a3);
                ushort4 ua = {h2u(a0), h2u(a1), h2u(a2), h2u(a3)};
                ushort4 ue = {h2u(e0), h2u(e1), h2u(e2), h2u(e3)};
                *(ushort4*)&xabuf[(s + 1) & 1][0][(prow + q * 8) * 136 + pc4] = ua;
                *(ushort4*)&xabuf[(s + 1) & 1][1][(prow + q * 8) * 136 + pc4] = ue;
            }
        }
        __syncthreads();   // B_mid

        // ---- step 3: LN-x prefetch; S: GEMM2(s); G: GEMM1(s+1) ----
        float2 pfln[2];
        if (mainsub) {
#pragma unroll
            for (int rr = 0; rr < 2; ++rr)
                pfln[rr] = *(const float2*)&xbase[(size_t)(tbase + 2 * w + rr) * 128 + lane * 2];
        }
        if (isS) {
            const _Float16* sp = (const _Float16*)&xabuf[s & 1][0][0];
            f32x4 acc[2];
            acc[0] = (f32x4){0.f, 0.f, 0.f, 0.f};
            acc[1] = (f32x4){0.f, 0.f, 0.f, 0.f};
#pragma unroll
            for (int ks = 0; ks < 8; ++ks) {
                half8 a = *(const half8*)&sp[fr * 264 + ks * 32 + fo8];
#pragma unroll
                for (int j = 0; j < 2; ++j) {
                    acc[j] = MFMA_F16(a, wf[(j * 8 + ks) * 2], acc[j]);
                    acc[j] = MFMA_F16(a, wf[(j * 8 + ks) * 2 + 1], acc[j]);
                }
            }
#pragma unroll
            for (int j = 0; j < 2; ++j) {
                int col = 32 * sg + 16 * j + fr;
#pragma unroll
                for (int r = 0; r < 4; ++r)
                    hbuf[s & 1][(qr + r) * 260 + col] = acc[j][r] + bias0[j];
            }
        } else if (s < 23) {
            const _Float16* xa0 = (const _Float16*)&xabuf[(s + 1) & 1][0][0];
            const _Float16* xa1 = (const _Float16*)&xabuf[(s + 1) & 1][1][0];
            f32x4 acc[4];
#pragma unroll
            for (int j = 0; j < 4; ++j) acc[j] = (f32x4){0.f, 0.f, 0.f, 0.f};
#pragma unroll
            for (int k0 = 0; k0 < 4; ++k0) {
                half8 a0 = *(const half8*)&xa0[fr * 136 + k0 * 32 + fo8];
                half8 a1 = *(const half8*)&xa1[fr * 136 + k0 * 32 + fo8];
#pragma unroll
                for (int j = 0; j < 4; ++j) {
                    acc[j] = MFMA_F16(a0, wf[(j * 4 + k0) * 2], acc[j]);
                    acc[j] = MFMA_F16(a0, wf[(j * 4 + k0) * 2 + 1], acc[j]);
                    acc[j] = MFMA_F16(a1, wf[(j * 4 + k0) * 2], acc[j]);
                }
            }
#pragma unroll
            for (int j = 0; j < 4; ++j) {
                int col = 64 * gg + 16 * j + fr;
#pragma unroll
                for (int r = 0; r < 4; ++r)
                    hbuf[(s + 1) & 1][(qr + r) * 260 + col] = acc[j][r] + bias0[j];
            }
            if (s < 22) {
#pragma unroll
                for (int q = 0; q < 2; ++q)
                    pfx[q] = *(const float4*)&xbase[(size_t)(tbase + 32 + prow + q * 8) * 128 + pc4];
            }
        }
        __syncthreads();   // B3

        // ---- step 5: scan2(s) (threads 0..127); s2 in place ----
        if (tid < 128) {
            float hh[16];
#pragma unroll
            for (int t = 0; t < 16; ++t) hh[t] = hbuf[s & 1][t * 260 + tid];
#pragma unroll
            for (int t = 0; t < 16; ++t) {
                float h = v2 + (hh[t] - v2) * 0.5f;
                bool sp = (h >= 1.0f);
                v2 = sp ? 0.0f : h;
                if (mainsub) hbuf[s & 1][t * 260 + tid] = sp ? 1.0f : 0.0f;
            }
        }

        // ---- step 6: LN + store (all 8 waves, 2 rows each) ----
        if (mainsub) {
            __syncthreads();   // B4
#pragma unroll
            for (int rr = 0; rr < 2; ++rr) {
                int row = 2 * w + rr;
                float2 s2v = *(const float2*)&hbuf[s & 1][row * 260 + lane * 2];
                float y0 = pfln[rr].x + s2v.x;
                float y1 = pfln[rr].y + s2v.y;
                float sum = y0 + y1;
                float ss = y0 * y0 + y1 * y1;
#pragma unroll
                for (int off = 32; off > 0; off >>= 1) {
                    sum += __shfl_xor(sum, off, 64);
                    ss  += __shfl_xor(ss, off, 64);
                }
                float mu = sum * (1.0f / 128.0f);
                float var = ss * (1.0f / 128.0f) - mu * mu;
                float inv = rsqrtf(var + 1e-5f);
                float2 o;
                o.x = (y0 - mu) * inv * wv.x + bbv.x;
                o.y = (y1 - mu) * inv * wv.y + bbv.y;
                *(float2*)&obase[(size_t)(tbase + row) * 128 + lane * 2] = o;
            }
        }
    }
}

extern "C" void kernel_launch(void* const* d_in, const int* in_sizes, int n_in,
                              void* d_out, int out_size, void* d_ws, size_t ws_size,
                              hipStream_t stream)
{
    const float* x   = (const float*)d_in[0];
    const float* W1  = (const float*)d_in[1];
    const float* b1  = (const float*)d_in[2];
    const float* W2  = (const float*)d_in[3];
    const float* b2  = (const float*)d_in[4];
    const float* lnw = (const float*)d_in[5];
    const float* lnb = (const float*)d_in[6];
    float* out = (float*)d_out;

    dim3 gM(8, 32);   // 256 blocks, 1/CU
    mega_kernel<<<gM, 512, 0, stream>>>(x, W1, W2, b1, b2, lnw, lnb, out);
}